// Round 4
// baseline (3942.559 us; speedup 1.0000x reference)
//
#include <hip/hip_runtime.h>
#include <hip/hip_bf16.h>
#include <math.h>

typedef __hip_bfloat16 bf16;

#define N_TOK 1024
#define DIM 2048
#define NHEADS 16
#define KVH 2
#define DH 128
#define GQ 8
#define NWIN 64
#define CMP_BLK 32
#define NCMP 65        // MEM_KV + NWIN
#define NFINE 16
#define SEL_BLK 64
#define T_TOT 320
#define CDIM 4096      // CMP_BLK*DH
#define SCALE 0.08838834764831845f

static __device__ __forceinline__ float b2f(bf16 v){ return __bfloat162float(v); }

// ---------------- RMSNorm: x fp32 [N,DIM] -> xn fp32 ----------------
__global__ __launch_bounds__(256) void rmsnorm_kernel(const float* __restrict__ x,
                                                      const float* __restrict__ g,
                                                      float* __restrict__ xn){
  int n = blockIdx.x, tid = threadIdx.x;
  __shared__ float red[256];
  const float* row = x + (size_t)n*DIM;
  float vals[8];
  float s = 0.f;
  #pragma unroll
  for (int i = 0; i < 8; ++i){ float v = row[tid + i*256]; vals[i] = v; s += v*v; }
  red[tid] = s; __syncthreads();
  for (int st = 128; st > 0; st >>= 1){ if (tid < st) red[tid] += red[tid+st]; __syncthreads(); }
  float scale = 1.0f / sqrtf(red[0]/(float)DIM + 1e-6f);
  #pragma unroll
  for (int i = 0; i < 8; ++i){
    int c = tid + i*256;
    xn[(size_t)n*DIM + c] = vals[i]*scale*g[c];
  }
}

// ---------------- Generic GEMM: C[M,N] = act(A[M,K] * B[K, ldb-sliced] + bias) ----------------
// A fp32 (a_is_bf16=0) or bf16 (=1), leading dim K. B fp32 leading dim ldb
// (caller pre-offsets B to the first column). act: 0 none, 1 relu, 2 sigmoid.
__global__ __launch_bounds__(256) void gemm_kernel(const void* __restrict__ Av, int a_is_bf16,
                                                   const float* __restrict__ B, int ldb,
                                                   const float* __restrict__ bias,
                                                   float* __restrict__ Cf,
                                                   bf16* __restrict__ Cb,
                                                   int M, int N, int K, int act){
  __shared__ __align__(16) float As[16*68];
  __shared__ __align__(16) float Bs[16*68];
  int tid = threadIdx.x;
  int tx = tid & 15, ty = tid >> 4;
  int m0 = blockIdx.y * 64, n0 = blockIdx.x * 64;
  const float* Af = (const float*)Av;
  const bf16*  Ab = (const bf16*)Av;
  float c[4][4] = {};
  for (int k0 = 0; k0 < K; k0 += 16){
    #pragma unroll
    for (int i = 0; i < 4; ++i){
      int idx = tid + i*256;
      int kk = idx & 15, m = idx >> 4;
      size_t aidx = (size_t)(m0+m)*K + k0 + kk;
      As[kk*68 + m] = a_is_bf16 ? b2f(Ab[aidx]) : Af[aidx];
    }
    #pragma unroll
    for (int i = 0; i < 4; ++i){
      int idx = tid + i*256;
      int nn = idx & 63, kk = idx >> 6;
      int col = n0 + nn;
      Bs[kk*68 + nn] = (col < N) ? B[(size_t)(k0+kk)*ldb + col] : 0.f;
    }
    __syncthreads();
    #pragma unroll
    for (int kk = 0; kk < 16; ++kk){
      float a[4], b[4];
      *(float4*)a = *(const float4*)&As[kk*68 + ty*4];
      *(float4*)b = *(const float4*)&Bs[kk*68 + tx*4];
      #pragma unroll
      for (int i = 0; i < 4; ++i)
        #pragma unroll
        for (int j = 0; j < 4; ++j)
          c[i][j] += a[i]*b[j];
    }
    __syncthreads();
  }
  #pragma unroll
  for (int i = 0; i < 4; ++i){
    int row = m0 + ty*4 + i;
    #pragma unroll
    for (int j = 0; j < 4; ++j){
      int col = n0 + tx*4 + j;
      if (col < N){
        float vv = c[i][j];
        if (bias) vv += bias[col];
        if (act == 1) vv = fmaxf(vv, 0.f);
        else if (act == 2) vv = 1.f/(1.f + expf(-vv));
        if (Cb) Cb[(size_t)row*N + col] = __float2bfloat16(vv);
        else    Cf[(size_t)row*N + col] = vv;
      }
    }
  }
}

// ---------------- RoPE: q fp32 [n][2048], kv fp32 [n][512] -> qr bf16 [n][2048], kr bf16 [n][256] ----
__global__ __launch_bounds__(256) void rope_kernel(const float* __restrict__ q,
    const float* __restrict__ kv, bf16* __restrict__ qr, bf16* __restrict__ kr){
  int n = blockIdx.x, tid = threadIdx.x;
  const float* qrow = q + (size_t)n*DIM;
  bf16* qrrow = qr + (size_t)n*DIM;
  #pragma unroll
  for (int i = 0; i < 4; ++i){
    int p = tid + i*256;
    int hd = p >> 6, ii = p & 63;
    float inv = powf(10000.f, -(float)ii/64.f);
    float ang = (float)n * inv;
    float cs = cosf(ang), sn = sinf(ang);
    float x1 = qrow[hd*DH + 2*ii], x2 = qrow[hd*DH + 2*ii + 1];
    qrrow[hd*DH + 2*ii]     = __float2bfloat16(x1*cs - x2*sn);
    qrrow[hd*DH + 2*ii + 1] = __float2bfloat16(x1*sn + x2*cs);
  }
  if (tid < 128){
    int h = tid >> 6, ii = tid & 63;
    float inv = powf(10000.f, -(float)ii/64.f);
    float ang = (float)n * inv;
    float cs = cosf(ang), sn = sinf(ang);
    const float* kvrow = kv + (size_t)n*512;
    float x1 = kvrow[h*DH + 2*ii], x2 = kvrow[h*DH + 2*ii + 1];
    bf16* krrow = kr + (size_t)n*256;
    krrow[h*DH + 2*ii]     = __float2bfloat16(x1*cs - x2*sn);
    krrow[h*DH + 2*ii + 1] = __float2bfloat16(x1*sn + x2*cs);
  }
}

// ---------------- Build compression-MLP input f [128][CDIM] (k: voff=0, v: voff=256) ----------------
__global__ __launch_bounds__(256) void build_f_kernel(const float* __restrict__ kv, int voff,
    const float* __restrict__ pos, float* __restrict__ f){
  int bw = blockIdx.x;           // h*NWIN + w
  int h = bw >> 6, w = bw & 63;
  int tid = threadIdx.x;
  for (int idx = tid; idx < CMP_BLK*DH; idx += 256){
    int j = idx >> 7, d = idx & 127;
    int t = w*16 + j - 16;       // padded window index
    float kvv = (t >= 0) ? kv[(size_t)t*512 + voff + h*DH + d] : 0.f;
    f[(size_t)bw*CDIM + idx] = kvv + pos[(h*CMP_BLK + j)*DH + d];
  }
}

// ---------------- Assemble ck/cv [KVH][NCMP][DH] with mem_kv at slot 0 ----------------
__global__ __launch_bounds__(256) void assemble_kernel(const float* __restrict__ ckb,
    const float* __restrict__ cvb, const float* __restrict__ mem_kv,
    float* __restrict__ ck, float* __restrict__ cv){
  int j = blockIdx.x;            // 0..64
  int tid = threadIdx.x;         // 256 = KVH*DH
  int h = tid >> 7, d = tid & 127;
  float kvx, vvx;
  if (j == 0){
    kvx = mem_kv[(0*KVH + h)*DH + d];
    vvx = mem_kv[(1*KVH + h)*DH + d];
  } else {
    kvx = ckb[((size_t)h*NWIN + (j-1))*DH + d];
    vvx = cvb[((size_t)h*NWIN + (j-1))*DH + d];
  }
  ck[((size_t)h*NCMP + j)*DH + d] = kvx;
  cv[((size_t)h*NCMP + j)*DH + d] = vvx;
}

// ---------------- Compressed attention (pre-rope q, fp32) + importance + top-4 selection ----------------
__global__ __launch_bounds__(256) void cmp_attn_kernel(const float* __restrict__ q,
    const float* __restrict__ ck, const float* __restrict__ cv,
    bf16* __restrict__ cmp_o, int* __restrict__ sel){
  int bx = blockIdx.x;
  int h = bx >> 10, n = bx & 1023;
  int tid = threadIdx.x;
  __shared__ float cks[NCMP*129];
  __shared__ float qs[GQ*DH];
  __shared__ float sims[GQ*66];
  __shared__ float red[GQ*32];
  __shared__ float impb[NFINE];
  for (int idx = tid; idx < NCMP*DH; idx += 256){
    int j = idx >> 7, d = idx & 127;
    cks[j*129 + d] = ck[((size_t)h*NCMP + j)*DH + d];
  }
  for (int idx = tid; idx < GQ*DH; idx += 256)
    qs[idx] = q[(size_t)n*DIM + h*(GQ*DH) + idx];
  __syncthreads();
  for (int p = tid; p < GQ*NCMP; p += 256){
    int g = p / NCMP, j = p % NCMP;
    float acc = 0.f;
    const float* qp = &qs[g*DH];
    const float* kp = &cks[j*129];
    #pragma unroll 4
    for (int d = 0; d < DH; ++d) acc += qp[d]*kp[d];
    sims[g*66 + j] = acc * SCALE;
  }
  __syncthreads();
  if (tid < NFINE){
    float s = 0.f;
    for (int g = 0; g < GQ; ++g)
      #pragma unroll
      for (int c = 0; c < 4; ++c)
        s += sims[g*66 + 1 + tid*4 + c];
    impb[tid] = s;
  }
  __syncthreads();
  if (tid == 0){
    int own = n >> 6;
    impb[own] = -1e30f;
    int selbuf[5];
    #pragma unroll
    for (int r = 0; r < 4; ++r){
      float best = -1e38f; int bi = 0;
      for (int f = 0; f < NFINE; ++f)
        if (impb[f] > best){ best = impb[f]; bi = f; }   // strict > : lowest index on ties
      selbuf[r] = bi; impb[bi] = -1e38f;
    }
    selbuf[4] = own;
    for (int r = 0; r < 5; ++r) sel[(size_t)(h*N_TOK + n)*8 + r] = selbuf[r];
  }
  int g = tid >> 5, lane = tid & 31;
  float m = -1e38f;
  for (int j = lane; j < NCMP; j += 32) m = fmaxf(m, sims[g*66 + j]);
  red[g*32 + lane] = m; __syncthreads();
  for (int st = 16; st > 0; st >>= 1){ if (lane < st) red[g*32+lane] = fmaxf(red[g*32+lane], red[g*32+lane+st]); __syncthreads(); }
  float gm = red[g*32]; __syncthreads();
  float ps = 0.f;
  for (int j = lane; j < NCMP; j += 32){ float e = expf(sims[g*66+j] - gm); sims[g*66+j] = e; ps += e; }
  red[g*32+lane] = ps; __syncthreads();
  for (int st = 16; st > 0; st >>= 1){ if (lane < st) red[g*32+lane] += red[g*32+lane+st]; __syncthreads(); }
  float inv = 1.f / red[g*32]; __syncthreads();
  for (int j = lane; j < NCMP; j += 32) sims[g*66+j] *= inv;
  __syncthreads();
  for (int p = tid; p < GQ*DH; p += 256){
    int gg = p >> 7, d = p & 127;
    float acc = 0.f;
    const float* cvp = cv + (size_t)h*NCMP*DH + d;
    for (int j = 0; j < NCMP; ++j) acc += sims[gg*66 + j] * cvp[j*DH];
    cmp_o[(size_t)n*DIM + (h*GQ + gg)*DH + d] = __float2bfloat16(acc);
  }
}

// ---------------- Fine (selected-block) attention: roped q/k (bf16), raw v (fp32 strided) ------------
__global__ __launch_bounds__(256) void fine_attn_kernel(const bf16* __restrict__ qr,
    const bf16* __restrict__ kr, const float* __restrict__ kv,
    const int* __restrict__ sel, bf16* __restrict__ fine_o){
  int bx = blockIdx.x;
  int h = bx >> 10, n = bx & 1023;
  int tid = threadIdx.x;
  __shared__ float kt[SEL_BLK*129];
  __shared__ float qs[GQ*DH];
  __shared__ float sims[GQ*321];
  __shared__ float red[GQ*32];
  int sel5[5];
  #pragma unroll
  for (int r = 0; r < 5; ++r){
    int b = sel[(size_t)(h*N_TOK + n)*8 + r];
    sel5[r] = (b < 0) ? 0 : (b > 15 ? 15 : b);
  }
  for (int idx = tid; idx < GQ*DH; idx += 256)
    qs[idx] = b2f(qr[(size_t)n*DIM + h*(GQ*DH) + idx]);
  for (int tile = 0; tile < 5; ++tile){
    int blk = sel5[tile];
    __syncthreads();
    for (int idx = tid; idx < SEL_BLK*DH; idx += 256){
      int tl = idx >> 7, d = idx & 127;
      kt[tl*129 + d] = b2f(kr[(size_t)(blk*SEL_BLK + tl)*256 + h*DH + d]);
    }
    __syncthreads();
    for (int p = tid; p < GQ*SEL_BLK; p += 256){
      int g = p >> 6, t = p & 63;
      float acc = 0.f;
      const float* qp = &qs[g*DH];
      const float* kp = &kt[t*129];
      #pragma unroll 4
      for (int d = 0; d < DH; ++d) acc += qp[d]*kp[d];
      sims[g*321 + tile*SEL_BLK + t] = acc * SCALE;
    }
  }
  __syncthreads();
  int g = tid >> 5, lane = tid & 31;
  float m = -1e38f;
  for (int t = lane; t < T_TOT; t += 32) m = fmaxf(m, sims[g*321 + t]);
  red[g*32+lane] = m; __syncthreads();
  for (int st = 16; st > 0; st >>= 1){ if (lane < st) red[g*32+lane] = fmaxf(red[g*32+lane], red[g*32+lane+st]); __syncthreads(); }
  float gm = red[g*32]; __syncthreads();
  float ps = 0.f;
  for (int t = lane; t < T_TOT; t += 32){ float e = expf(sims[g*321+t] - gm); sims[g*321+t] = e; ps += e; }
  red[g*32+lane] = ps; __syncthreads();
  for (int st = 16; st > 0; st >>= 1){ if (lane < st) red[g*32+lane] += red[g*32+lane+st]; __syncthreads(); }
  float inv = 1.f / red[g*32]; __syncthreads();
  for (int t = lane; t < T_TOT; t += 32) sims[g*321+t] *= inv;
  float acc[4] = {0.f,0.f,0.f,0.f};
  for (int tile = 0; tile < 5; ++tile){
    int blk = sel5[tile];
    __syncthreads();
    for (int idx = tid; idx < SEL_BLK*DH; idx += 256){
      int tl = idx >> 7, d = idx & 127;
      kt[tl*129 + d] = kv[(size_t)(blk*SEL_BLK + tl)*512 + 256 + h*DH + d];
    }
    __syncthreads();
    #pragma unroll
    for (int i = 0; i < 4; ++i){
      int p = tid + i*256;
      int gg = p >> 7, d = p & 127;
      float a = acc[i];
      const float* sp = &sims[gg*321 + tile*SEL_BLK];
      const float* vp = &kt[d];
      for (int t = 0; t < SEL_BLK; ++t) a += sp[t]*vp[t*129];
      acc[i] = a;
    }
  }
  #pragma unroll
  for (int i = 0; i < 4; ++i){
    int p = tid + i*256;
    int gg = p >> 7, d = p & 127;
    fine_o[(size_t)n*DIM + (h*GQ + gg)*DH + d] = __float2bfloat16(acc[i]);
  }
}

// ---------------- Sliding-window attention, flash-style online softmax (32-query tiles) -------------
__global__ __launch_bounds__(256) void slide_attn_kernel(const bf16* __restrict__ qr,
    const bf16* __restrict__ kr, const float* __restrict__ kv,
    bf16* __restrict__ slide_o){
  int hq = blockIdx.y;          // 16 heads
  int qt = blockIdx.x;          // 32 query tiles of 32
  int h = hq >> 3;
  int n0 = qt * 32;
  int tid = threadIdx.x;
  __shared__ float qs[32*DH];
  __shared__ float kt[64*129];
  __shared__ float st[32*65];
  __shared__ float red[256];
  __shared__ float mrow[32], lrow[32], arow[32];
  for (int i = 0; i < 16; ++i){
    int idx = tid + i*256;
    qs[idx] = b2f(qr[(size_t)(n0 + (idx>>7))*DIM + hq*DH + (idx & 127)]);
  }
  if (tid < 32){ mrow[tid] = -1e30f; lrow[tid] = 0.f; }
  float acc[16];
  #pragma unroll
  for (int i = 0; i < 16; ++i) acc[i] = 0.f;
  int kstart = n0 - 128;
  int r = tid >> 3, lane = tid & 7;
  for (int tile = 0; tile < 5; ++tile){
    __syncthreads();
    for (int i = 0; i < 32; ++i){
      int idx = tid + i*256;
      int tl = idx >> 7, d = idx & 127;
      int kg = kstart + tile*64 + tl;
      kt[tl*129 + d] = (kg >= 0 && kg < N_TOK) ? b2f(kr[(size_t)kg*256 + h*DH + d]) : 0.f;
    }
    __syncthreads();
    for (int i = 0; i < 8; ++i){
      int p = tid + i*256;
      int qi = p >> 6, t = p & 63;
      int kg = kstart + tile*64 + t;
      int qg = n0 + qi;
      int diff = qg - kg;
      bool valid = (kg >= 0) && (kg < N_TOK) && (diff <= 128) && (diff >= -128);
      float ov;
      if (valid){
        float a = 0.f;
        const float* qp = &qs[qi*DH];
        const float* kp = &kt[t*129];
        #pragma unroll 4
        for (int d = 0; d < DH; ++d) a += qp[d]*kp[d];
        ov = a * SCALE;
      } else ov = -1e30f;
      st[qi*65 + t] = ov;
    }
    __syncthreads();
    float m = -1e30f;
    for (int t = lane; t < 64; t += 8) m = fmaxf(m, st[r*65 + t]);
    red[tid] = m; __syncthreads();
    if (lane < 4) red[tid] = fmaxf(red[tid], red[tid+4]);
    __syncthreads();
    if (lane < 2) red[tid] = fmaxf(red[tid], red[tid+2]);
    __syncthreads();
    if (lane == 0){
      float mt = fmaxf(red[tid], red[tid+1]);
      float mold = mrow[r];
      float mnew = fmaxf(fmaxf(mold, mt), -1e20f);
      arow[r] = expf(mold - mnew);
      mrow[r] = mnew;
    }
    __syncthreads();
    float mnew = mrow[r];
    float ps = 0.f;
    for (int t = lane; t < 64; t += 8){
      float e = expf(st[r*65 + t] - mnew);
      st[r*65 + t] = e; ps += e;
    }
    red[tid] = ps; __syncthreads();
    if (lane < 4) red[tid] += red[tid+4];
    __syncthreads();
    if (lane < 2) red[tid] += red[tid+2];
    __syncthreads();
    if (lane == 0) lrow[r] = lrow[r]*arow[r] + red[tid] + red[tid+1];
    __syncthreads();
    for (int i = 0; i < 32; ++i){
      int idx = tid + i*256;
      int tl = idx >> 7, d = idx & 127;
      int kg = kstart + tile*64 + tl;
      kt[tl*129 + d] = (kg >= 0 && kg < N_TOK) ? kv[(size_t)kg*512 + 256 + h*DH + d] : 0.f;
    }
    __syncthreads();
    #pragma unroll
    for (int i = 0; i < 16; ++i){
      int p = tid + i*256;
      int qi = p >> 7, d = p & 127;
      float a = acc[i] * arow[qi];
      const float* sp = &st[qi*65];
      const float* vp = &kt[d];
      for (int t = 0; t < 64; ++t) a += sp[t]*vp[t*129];
      acc[i] = a;
    }
  }
  #pragma unroll
  for (int i = 0; i < 16; ++i){
    int p = tid + i*256;
    int qi = p >> 7, d = p & 127;
    slide_o[(size_t)(n0 + qi)*DIM + hq*DH + d] = __float2bfloat16(acc[i] / lrow[qi]);
  }
}

// ---------------- Gated combine -> ocomb bf16 [n][2048] ----------------
__global__ __launch_bounds__(256) void combine_kernel(const bf16* __restrict__ cmp_o,
    const bf16* __restrict__ fine_o, const bf16* __restrict__ slide_o,
    const float* __restrict__ gates, bf16* __restrict__ ocomb){
  int n = blockIdx.x, tid = threadIdx.x;
  #pragma unroll
  for (int i = 0; i < 8; ++i){
    int c = tid + i*256;
    int hq = c >> 7;
    float g0 = gates[(size_t)n*48 + hq*3 + 0];
    float g1 = gates[(size_t)n*48 + hq*3 + 1];
    float g2 = gates[(size_t)n*48 + hq*3 + 2];
    size_t idx = (size_t)n*DIM + c;
    ocomb[idx] = __float2bfloat16(b2f(cmp_o[idx])*g0 + b2f(fine_o[idx])*g1 + b2f(slide_o[idx])*g2);
  }
}

extern "C" void kernel_launch(void* const* d_in, const int* in_sizes, int n_in,
                              void* d_out, int out_size, void* d_ws, size_t ws_size,
                              hipStream_t stream)
{
  // Reference dtypes are all float32 -> const float* (per harness contract).
  const float* x      = (const float*)d_in[0];
  const float* g_norm = (const float*)d_in[1];
  const float* W_qkv  = (const float*)d_in[2];
  const float* k_pos  = (const float*)d_in[3];
  const float* v_pos  = (const float*)d_in[4];
  const float* mem_kv = (const float*)d_in[5];
  const float* Wk1    = (const float*)d_in[6];
  const float* bk1    = (const float*)d_in[7];
  const float* Wk2    = (const float*)d_in[8];
  const float* bk2    = (const float*)d_in[9];
  const float* Wv1    = (const float*)d_in[10];
  const float* bv1    = (const float*)d_in[11];
  const float* Wv2    = (const float*)d_in[12];
  const float* bv2    = (const float*)d_in[13];
  const float* Wg     = (const float*)d_in[14];
  const float* bg     = (const float*)d_in[15];
  const float* W_out  = (const float*)d_in[16];
  float* out = (float*)d_out;
  (void)ws_size; (void)in_sizes; (void)n_in; (void)out_size;

  // ---- Workspace layout (bytes), total ~22.5 MB, aggressive region reuse ----
  char* base = (char*)d_ws;
  float* q     = (float*)(base + 0);                 // 8 MB [n][2048] fp32, live -> cmp_attn
  float* xn    = (float*)(base + 8388608);           // 8 MB fp32, live -> kv GEMM
  bf16*  qr    = (bf16*) (base + 8388608);           // 4 MB (over xn, after xn dead)
  bf16*  kr    = (bf16*) (base + 12582912);          // 0.5 MB
  bf16*  ocomb = (bf16*) (base + 8388608);           // 4 MB (over qr, after slide)
  float* kv    = (float*)(base + 16777216);          // 2 MB [n][512] fp32
  float* fbuf  = (float*)(base + 18874368);          // 2 MB fk / fv
  float* hbuf  = (float*)(base + 20971520);          // 2 MB hk / hv
  bf16*  cmp_o = (bf16*) (base + 18874368);          // 4 MB (over fbuf+hbuf, after MLPs)
  float* ckb   = (float*)(base + 23068672);          // 64 KB
  float* cvb   = (float*)(base + 23134208);          // 64 KB
  float* ck    = (float*)(base + 23199744);          // 65 KB
  float* cv    = (float*)(base + 23266304);          // 65 KB
  float* gates = (float*)(base + 23332864);          // 192 KB
  int*   sel   = (int*)  (base + 23529472);          // 64 KB   (end: 23,595,008 B)
  bf16*  fine_o  = (bf16*)(base + 0);                // 4 MB (over q, after cmp_attn)
  bf16*  slide_o = (bf16*)(base + 4194304);          // 4 MB (over q upper half)

  rmsnorm_kernel<<<N_TOK, 256, 0, stream>>>(x, g_norm, xn);
  // gates = sigmoid(xn @ Wg + bg)   [1024 x 48]
  gemm_kernel<<<dim3(1, 16), 256, 0, stream>>>(xn, 0, Wg, 48, bg, gates, nullptr, N_TOK, 48, DIM, 2);
  // q = xn @ W_qkv[:, 0:2048]       [1024 x 2048] fp32 (selection-critical)
  gemm_kernel<<<dim3(32, 16), 256, 0, stream>>>(xn, 0, W_qkv, 2560, nullptr, q, nullptr, N_TOK, 2048, DIM, 0);
  // kv = xn @ W_qkv[:, 2048:2560]   [1024 x 512] fp32
  gemm_kernel<<<dim3(8, 16), 256, 0, stream>>>(xn, 0, W_qkv + 2048, 2560, nullptr, kv, nullptr, N_TOK, 512, DIM, 0);
  // qr, kr (bf16) — xn now dead
  rope_kernel<<<N_TOK, 256, 0, stream>>>(q, kv, qr, kr);
  // compression MLPs (fp32, selection-critical via ck)
  build_f_kernel<<<KVH*NWIN, 256, 0, stream>>>(kv, 0, k_pos, fbuf);
  gemm_kernel<<<dim3(64, 2), 256, 0, stream>>>(fbuf, 0, Wk1, CDIM, bk1, hbuf, nullptr, KVH*NWIN, CDIM, CDIM, 1);
  gemm_kernel<<<dim3(2, 2), 256, 0, stream>>>(hbuf, 0, Wk2, DH, bk2, ckb, nullptr, KVH*NWIN, DH, CDIM, 0);
  build_f_kernel<<<KVH*NWIN, 256, 0, stream>>>(kv, 256, v_pos, fbuf);
  gemm_kernel<<<dim3(64, 2), 256, 0, stream>>>(fbuf, 0, Wv1, CDIM, bv1, hbuf, nullptr, KVH*NWIN, CDIM, CDIM, 1);
  gemm_kernel<<<dim3(2, 2), 256, 0, stream>>>(hbuf, 0, Wv2, DH, bv2, cvb, nullptr, KVH*NWIN, DH, CDIM, 0);
  assemble_kernel<<<NCMP, 256, 0, stream>>>(ckb, cvb, mem_kv, ck, cv);
  // compressed attention + selection (fbuf/hbuf dead -> cmp_o)
  cmp_attn_kernel<<<KVH*N_TOK, 256, 0, stream>>>(q, ck, cv, cmp_o, sel);
  // fine attention (q dead -> fine_o over q region)
  fine_attn_kernel<<<KVH*N_TOK, 256, 0, stream>>>(qr, kr, kv, sel, fine_o);
  // sliding attention (-> slide_o over q upper half)
  slide_attn_kernel<<<dim3(32, 16), 256, 0, stream>>>(qr, kr, kv, slide_o);
  // combine (qr dead -> ocomb over qr)
  combine_kernel<<<N_TOK, 256, 0, stream>>>(cmp_o, fine_o, slide_o, gates, ocomb);
  // out = ocomb @ W_out  (bf16 A, fp32 out)
  gemm_kernel<<<dim3(32, 16), 256, 0, stream>>>(ocomb, 1, W_out, DIM, nullptr, out, nullptr, N_TOK, DIM, DIM, 0);
}

// Round 5
// 1640.636 us; speedup vs baseline: 2.4031x; 2.4031x over previous
//
#include <hip/hip_runtime.h>
#include <hip/hip_bf16.h>
#include <math.h>

typedef __hip_bfloat16 bf16;

#define N_TOK 1024
#define DIM 2048
#define NHEADS 16
#define KVH 2
#define DH 128
#define GQ 8
#define NWIN 64
#define CMP_BLK 32
#define NCMP 65        // MEM_KV + NWIN
#define NFINE 16
#define SEL_BLK 64
#define T_TOT 320
#define CDIM 4096      // CMP_BLK*DH
#define SCALE 0.08838834764831845f

static __device__ __forceinline__ float b2f(bf16 v){ return __bfloat162float(v); }

// ---------------- RMSNorm: x fp32 [N,DIM] -> xn fp32 ----------------
__global__ __launch_bounds__(256) void rmsnorm_kernel(const float* __restrict__ x,
                                                      const float* __restrict__ g,
                                                      float* __restrict__ xn){
  int n = blockIdx.x, tid = threadIdx.x;
  __shared__ float red[256];
  const float* row = x + (size_t)n*DIM;
  float vals[8];
  float s = 0.f;
  #pragma unroll
  for (int i = 0; i < 8; ++i){ float v = row[tid + i*256]; vals[i] = v; s += v*v; }
  red[tid] = s; __syncthreads();
  for (int st = 128; st > 0; st >>= 1){ if (tid < st) red[tid] += red[tid+st]; __syncthreads(); }
  float scale = 1.0f / sqrtf(red[0]/(float)DIM + 1e-6f);
  #pragma unroll
  for (int i = 0; i < 8; ++i){
    int c = tid + i*256;
    xn[(size_t)n*DIM + c] = vals[i]*scale*g[c];
  }
}

// ---------------- Split-K GEMM: C[M,N] += A_chunk[M,Kc] * B_chunk[Kc,N] (atomicAdd) ----------------
// A fp32 (a_is_bf16=0) or bf16 (=1), leading dim K. Optional A-load fold:
// A' = relu(A + afold[kcol]) (only meaningful for fp32 A). B fp32 leading dim ldb
// (caller pre-offsets B to the first column). grid = (ceil(N/64), M/64, K/kchunk).
// No bias/activation here — folded downstream by callers. C must be pre-zeroed.
__global__ __launch_bounds__(256) void gemm_splitk_kernel(const void* __restrict__ Av, int a_is_bf16,
                                                          const float* __restrict__ afold,
                                                          const float* __restrict__ B, int ldb,
                                                          float* __restrict__ C,
                                                          int M, int N, int K, int kchunk){
  __shared__ __align__(16) float As[16*68];
  __shared__ __align__(16) float Bs[16*68];
  int tid = threadIdx.x;
  int tx = tid & 15, ty = tid >> 4;
  int m0 = blockIdx.y * 64, n0 = blockIdx.x * 64;
  int kz = blockIdx.z * kchunk;
  const float* Af = (const float*)Av;
  const bf16*  Ab = (const bf16*)Av;
  float c[4][4] = {};
  for (int k0 = kz; k0 < kz + kchunk; k0 += 16){
    #pragma unroll
    for (int i = 0; i < 4; ++i){
      int idx = tid + i*256;
      int kk = idx & 15, m = idx >> 4;
      size_t aidx = (size_t)(m0+m)*K + k0 + kk;
      float av = a_is_bf16 ? b2f(Ab[aidx]) : Af[aidx];
      if (afold) av = fmaxf(av + afold[k0+kk], 0.f);
      As[kk*68 + m] = av;
    }
    #pragma unroll
    for (int i = 0; i < 4; ++i){
      int idx = tid + i*256;
      int nn = idx & 63, kk = idx >> 6;
      int col = n0 + nn;
      Bs[kk*68 + nn] = (col < N) ? B[(size_t)(k0+kk)*ldb + col] : 0.f;
    }
    __syncthreads();
    #pragma unroll
    for (int kk = 0; kk < 16; ++kk){
      float a[4], b[4];
      *(float4*)a = *(const float4*)&As[kk*68 + ty*4];
      *(float4*)b = *(const float4*)&Bs[kk*68 + tx*4];
      #pragma unroll
      for (int i = 0; i < 4; ++i)
        #pragma unroll
        for (int j = 0; j < 4; ++j)
          c[i][j] += a[i]*b[j];
    }
    __syncthreads();
  }
  #pragma unroll
  for (int i = 0; i < 4; ++i){
    int row = m0 + ty*4 + i;
    #pragma unroll
    for (int j = 0; j < 4; ++j){
      int col = n0 + tx*4 + j;
      if (col < N) atomicAdd(&C[(size_t)row*N + col], c[i][j]);
    }
  }
}

// ---------------- RoPE: q fp32 [n][2048], kv fp32 [n][512] -> qr bf16 [n][2048], kr bf16 [n][256] ----
__global__ __launch_bounds__(256) void rope_kernel(const float* __restrict__ q,
    const float* __restrict__ kv, bf16* __restrict__ qr, bf16* __restrict__ kr){
  int n = blockIdx.x, tid = threadIdx.x;
  const float* qrow = q + (size_t)n*DIM;
  bf16* qrrow = qr + (size_t)n*DIM;
  #pragma unroll
  for (int i = 0; i < 4; ++i){
    int p = tid + i*256;
    int hd = p >> 6, ii = p & 63;
    float inv = powf(10000.f, -(float)ii/64.f);
    float ang = (float)n * inv;
    float cs = cosf(ang), sn = sinf(ang);
    float x1 = qrow[hd*DH + 2*ii], x2 = qrow[hd*DH + 2*ii + 1];
    qrrow[hd*DH + 2*ii]     = __float2bfloat16(x1*cs - x2*sn);
    qrrow[hd*DH + 2*ii + 1] = __float2bfloat16(x1*sn + x2*cs);
  }
  if (tid < 128){
    int h = tid >> 6, ii = tid & 63;
    float inv = powf(10000.f, -(float)ii/64.f);
    float ang = (float)n * inv;
    float cs = cosf(ang), sn = sinf(ang);
    const float* kvrow = kv + (size_t)n*512;
    float x1 = kvrow[h*DH + 2*ii], x2 = kvrow[h*DH + 2*ii + 1];
    bf16* krrow = kr + (size_t)n*256;
    krrow[h*DH + 2*ii]     = __float2bfloat16(x1*cs - x2*sn);
    krrow[h*DH + 2*ii + 1] = __float2bfloat16(x1*sn + x2*cs);
  }
}

// ---------------- Build compression-MLP input f [128][CDIM] (k: voff=0, v: voff=256) ----------------
__global__ __launch_bounds__(256) void build_f_kernel(const float* __restrict__ kv, int voff,
    const float* __restrict__ pos, float* __restrict__ f){
  int bw = blockIdx.x;           // h*NWIN + w
  int h = bw >> 6, w = bw & 63;
  int tid = threadIdx.x;
  for (int idx = tid; idx < CMP_BLK*DH; idx += 256){
    int j = idx >> 7, d = idx & 127;
    int t = w*16 + j - 16;       // padded window index
    float kvv = (t >= 0) ? kv[(size_t)t*512 + voff + h*DH + d] : 0.f;
    f[(size_t)bw*CDIM + idx] = kvv + pos[(h*CMP_BLK + j)*DH + d];
  }
}

// ---------------- Assemble ck/cv [KVH][NCMP][DH]; MLP second bias folded here ----------------
__global__ __launch_bounds__(256) void assemble_kernel(const float* __restrict__ ckb,
    const float* __restrict__ cvb, const float* __restrict__ mem_kv,
    const float* __restrict__ bk2, const float* __restrict__ bv2,
    float* __restrict__ ck, float* __restrict__ cv){
  int j = blockIdx.x;            // 0..64
  int tid = threadIdx.x;         // 256 = KVH*DH
  int h = tid >> 7, d = tid & 127;
  float kvx, vvx;
  if (j == 0){
    kvx = mem_kv[(0*KVH + h)*DH + d];
    vvx = mem_kv[(1*KVH + h)*DH + d];
  } else {
    kvx = ckb[((size_t)h*NWIN + (j-1))*DH + d] + bk2[d];
    vvx = cvb[((size_t)h*NWIN + (j-1))*DH + d] + bv2[d];
  }
  ck[((size_t)h*NCMP + j)*DH + d] = kvx;
  cv[((size_t)h*NCMP + j)*DH + d] = vvx;
}

// ---------------- Compressed attention (pre-rope q, fp32) + importance + top-4 selection ----------------
__global__ __launch_bounds__(256) void cmp_attn_kernel(const float* __restrict__ q,
    const float* __restrict__ ck, const float* __restrict__ cv,
    bf16* __restrict__ cmp_o, int* __restrict__ sel){
  int bx = blockIdx.x;
  int h = bx >> 10, n = bx & 1023;
  int tid = threadIdx.x;
  __shared__ float cks[NCMP*129];
  __shared__ float qs[GQ*DH];
  __shared__ float sims[GQ*66];
  __shared__ float red[GQ*32];
  __shared__ float impb[NFINE];
  for (int idx = tid; idx < NCMP*DH; idx += 256){
    int j = idx >> 7, d = idx & 127;
    cks[j*129 + d] = ck[((size_t)h*NCMP + j)*DH + d];
  }
  for (int idx = tid; idx < GQ*DH; idx += 256)
    qs[idx] = q[(size_t)n*DIM + h*(GQ*DH) + idx];
  __syncthreads();
  for (int p = tid; p < GQ*NCMP; p += 256){
    int g = p / NCMP, j = p % NCMP;
    float acc = 0.f;
    const float* qp = &qs[g*DH];
    const float* kp = &cks[j*129];
    #pragma unroll 4
    for (int d = 0; d < DH; ++d) acc += qp[d]*kp[d];
    sims[g*66 + j] = acc * SCALE;
  }
  __syncthreads();
  if (tid < NFINE){
    float s = 0.f;
    for (int g = 0; g < GQ; ++g)
      #pragma unroll
      for (int c = 0; c < 4; ++c)
        s += sims[g*66 + 1 + tid*4 + c];
    impb[tid] = s;
  }
  __syncthreads();
  if (tid == 0){
    int own = n >> 6;
    impb[own] = -1e30f;
    int selbuf[5];
    #pragma unroll
    for (int r = 0; r < 4; ++r){
      float best = -1e38f; int bi = 0;
      for (int f = 0; f < NFINE; ++f)
        if (impb[f] > best){ best = impb[f]; bi = f; }   // strict > : lowest index on ties
      selbuf[r] = bi; impb[bi] = -1e38f;
    }
    selbuf[4] = own;
    for (int r = 0; r < 5; ++r) sel[(size_t)(h*N_TOK + n)*8 + r] = selbuf[r];
  }
  int g = tid >> 5, lane = tid & 31;
  float m = -1e38f;
  for (int j = lane; j < NCMP; j += 32) m = fmaxf(m, sims[g*66 + j]);
  red[g*32 + lane] = m; __syncthreads();
  for (int st = 16; st > 0; st >>= 1){ if (lane < st) red[g*32+lane] = fmaxf(red[g*32+lane], red[g*32+lane+st]); __syncthreads(); }
  float gm = red[g*32]; __syncthreads();
  float ps = 0.f;
  for (int j = lane; j < NCMP; j += 32){ float e = expf(sims[g*66+j] - gm); sims[g*66+j] = e; ps += e; }
  red[g*32+lane] = ps; __syncthreads();
  for (int st = 16; st > 0; st >>= 1){ if (lane < st) red[g*32+lane] += red[g*32+lane+st]; __syncthreads(); }
  float inv = 1.f / red[g*32]; __syncthreads();
  for (int j = lane; j < NCMP; j += 32) sims[g*66+j] *= inv;
  __syncthreads();
  for (int p = tid; p < GQ*DH; p += 256){
    int gg = p >> 7, d = p & 127;
    float acc = 0.f;
    const float* cvp = cv + (size_t)h*NCMP*DH + d;
    for (int j = 0; j < NCMP; ++j) acc += sims[gg*66 + j] * cvp[j*DH];
    cmp_o[(size_t)n*DIM + (h*GQ + gg)*DH + d] = __float2bfloat16(acc);
  }
}

// ---------------- Fine (selected-block) attention: roped q/k (bf16), raw v (fp32 strided) ------------
__global__ __launch_bounds__(256) void fine_attn_kernel(const bf16* __restrict__ qr,
    const bf16* __restrict__ kr, const float* __restrict__ kv,
    const int* __restrict__ sel, bf16* __restrict__ fine_o){
  int bx = blockIdx.x;
  int h = bx >> 10, n = bx & 1023;
  int tid = threadIdx.x;
  __shared__ float kt[SEL_BLK*129];
  __shared__ float qs[GQ*DH];
  __shared__ float sims[GQ*321];
  __shared__ float red[GQ*32];
  int sel5[5];
  #pragma unroll
  for (int r = 0; r < 5; ++r){
    int b = sel[(size_t)(h*N_TOK + n)*8 + r];
    sel5[r] = (b < 0) ? 0 : (b > 15 ? 15 : b);
  }
  for (int idx = tid; idx < GQ*DH; idx += 256)
    qs[idx] = b2f(qr[(size_t)n*DIM + h*(GQ*DH) + idx]);
  for (int tile = 0; tile < 5; ++tile){
    int blk = sel5[tile];
    __syncthreads();
    for (int idx = tid; idx < SEL_BLK*DH; idx += 256){
      int tl = idx >> 7, d = idx & 127;
      kt[tl*129 + d] = b2f(kr[(size_t)(blk*SEL_BLK + tl)*256 + h*DH + d]);
    }
    __syncthreads();
    for (int p = tid; p < GQ*SEL_BLK; p += 256){
      int g = p >> 6, t = p & 63;
      float acc = 0.f;
      const float* qp = &qs[g*DH];
      const float* kp = &kt[t*129];
      #pragma unroll 4
      for (int d = 0; d < DH; ++d) acc += qp[d]*kp[d];
      sims[g*321 + tile*SEL_BLK + t] = acc * SCALE;
    }
  }
  __syncthreads();
  int g = tid >> 5, lane = tid & 31;
  float m = -1e38f;
  for (int t = lane; t < T_TOT; t += 32) m = fmaxf(m, sims[g*321 + t]);
  red[g*32+lane] = m; __syncthreads();
  for (int st = 16; st > 0; st >>= 1){ if (lane < st) red[g*32+lane] = fmaxf(red[g*32+lane], red[g*32+lane+st]); __syncthreads(); }
  float gm = red[g*32]; __syncthreads();
  float ps = 0.f;
  for (int t = lane; t < T_TOT; t += 32){ float e = expf(sims[g*321+t] - gm); sims[g*321+t] = e; ps += e; }
  red[g*32+lane] = ps; __syncthreads();
  for (int st = 16; st > 0; st >>= 1){ if (lane < st) red[g*32+lane] += red[g*32+lane+st]; __syncthreads(); }
  float inv = 1.f / red[g*32]; __syncthreads();
  for (int t = lane; t < T_TOT; t += 32) sims[g*321+t] *= inv;
  float acc[4] = {0.f,0.f,0.f,0.f};
  for (int tile = 0; tile < 5; ++tile){
    int blk = sel5[tile];
    __syncthreads();
    for (int idx = tid; idx < SEL_BLK*DH; idx += 256){
      int tl = idx >> 7, d = idx & 127;
      kt[tl*129 + d] = kv[(size_t)(blk*SEL_BLK + tl)*512 + 256 + h*DH + d];
    }
    __syncthreads();
    #pragma unroll
    for (int i = 0; i < 4; ++i){
      int p = tid + i*256;
      int gg = p >> 7, d = p & 127;
      float a = acc[i];
      const float* sp = &sims[gg*321 + tile*SEL_BLK];
      const float* vp = &kt[d];
      for (int t = 0; t < SEL_BLK; ++t) a += sp[t]*vp[t*129];
      acc[i] = a;
    }
  }
  #pragma unroll
  for (int i = 0; i < 4; ++i){
    int p = tid + i*256;
    int gg = p >> 7, d = p & 127;
    fine_o[(size_t)n*DIM + (h*GQ + gg)*DH + d] = __float2bfloat16(acc[i]);
  }
}

// ---------------- Sliding-window attention, flash-style online softmax (32-query tiles) -------------
__global__ __launch_bounds__(256) void slide_attn_kernel(const bf16* __restrict__ qr,
    const bf16* __restrict__ kr, const float* __restrict__ kv,
    bf16* __restrict__ slide_o){
  int hq = blockIdx.y;          // 16 heads
  int qt = blockIdx.x;          // 32 query tiles of 32
  int h = hq >> 3;
  int n0 = qt * 32;
  int tid = threadIdx.x;
  __shared__ float qs[32*DH];
  __shared__ float kt[64*129];
  __shared__ float st[32*65];
  __shared__ float red[256];
  __shared__ float mrow[32], lrow[32], arow[32];
  for (int i = 0; i < 16; ++i){
    int idx = tid + i*256;
    qs[idx] = b2f(qr[(size_t)(n0 + (idx>>7))*DIM + hq*DH + (idx & 127)]);
  }
  if (tid < 32){ mrow[tid] = -1e30f; lrow[tid] = 0.f; }
  float acc[16];
  #pragma unroll
  for (int i = 0; i < 16; ++i) acc[i] = 0.f;
  int kstart = n0 - 128;
  int r = tid >> 3, lane = tid & 7;
  for (int tile = 0; tile < 5; ++tile){
    __syncthreads();
    for (int i = 0; i < 32; ++i){
      int idx = tid + i*256;
      int tl = idx >> 7, d = idx & 127;
      int kg = kstart + tile*64 + tl;
      kt[tl*129 + d] = (kg >= 0 && kg < N_TOK) ? b2f(kr[(size_t)kg*256 + h*DH + d]) : 0.f;
    }
    __syncthreads();
    for (int i = 0; i < 8; ++i){
      int p = tid + i*256;
      int qi = p >> 6, t = p & 63;
      int kg = kstart + tile*64 + t;
      int qg = n0 + qi;
      int diff = qg - kg;
      bool valid = (kg >= 0) && (kg < N_TOK) && (diff <= 128) && (diff >= -128);
      float ov;
      if (valid){
        float a = 0.f;
        const float* qp = &qs[qi*DH];
        const float* kp = &kt[t*129];
        #pragma unroll 4
        for (int d = 0; d < DH; ++d) a += qp[d]*kp[d];
        ov = a * SCALE;
      } else ov = -1e30f;
      st[qi*65 + t] = ov;
    }
    __syncthreads();
    float m = -1e30f;
    for (int t = lane; t < 64; t += 8) m = fmaxf(m, st[r*65 + t]);
    red[tid] = m; __syncthreads();
    if (lane < 4) red[tid] = fmaxf(red[tid], red[tid+4]);
    __syncthreads();
    if (lane < 2) red[tid] = fmaxf(red[tid], red[tid+2]);
    __syncthreads();
    if (lane == 0){
      float mt = fmaxf(red[tid], red[tid+1]);
      float mold = mrow[r];
      float mnew = fmaxf(fmaxf(mold, mt), -1e20f);
      arow[r] = expf(mold - mnew);
      mrow[r] = mnew;
    }
    __syncthreads();
    float mnew = mrow[r];
    float ps = 0.f;
    for (int t = lane; t < 64; t += 8){
      float e = expf(st[r*65 + t] - mnew);
      st[r*65 + t] = e; ps += e;
    }
    red[tid] = ps; __syncthreads();
    if (lane < 4) red[tid] += red[tid+4];
    __syncthreads();
    if (lane < 2) red[tid] += red[tid+2];
    __syncthreads();
    if (lane == 0) lrow[r] = lrow[r]*arow[r] + red[tid] + red[tid+1];
    __syncthreads();
    for (int i = 0; i < 32; ++i){
      int idx = tid + i*256;
      int tl = idx >> 7, d = idx & 127;
      int kg = kstart + tile*64 + tl;
      kt[tl*129 + d] = (kg >= 0 && kg < N_TOK) ? kv[(size_t)kg*512 + 256 + h*DH + d] : 0.f;
    }
    __syncthreads();
    #pragma unroll
    for (int i = 0; i < 16; ++i){
      int p = tid + i*256;
      int qi = p >> 7, d = p & 127;
      float a = acc[i] * arow[qi];
      const float* sp = &st[qi*65];
      const float* vp = &kt[d];
      for (int t = 0; t < 64; ++t) a += sp[t]*vp[t*129];
      acc[i] = a;
    }
  }
  #pragma unroll
  for (int i = 0; i < 16; ++i){
    int p = tid + i*256;
    int qi = p >> 7, d = p & 127;
    slide_o[(size_t)(n0 + qi)*DIM + hq*DH + d] = __float2bfloat16(acc[i] / lrow[qi]);
  }
}

// ---------------- Gated combine; gate bias+sigmoid folded here -> ocomb bf16 [n][2048] --------------
__global__ __launch_bounds__(256) void combine_kernel(const bf16* __restrict__ cmp_o,
    const bf16* __restrict__ fine_o, const bf16* __restrict__ slide_o,
    const float* __restrict__ graw, const float* __restrict__ bg,
    bf16* __restrict__ ocomb){
  int n = blockIdx.x, tid = threadIdx.x;
  #pragma unroll
  for (int i = 0; i < 8; ++i){
    int c = tid + i*256;
    int hq = c >> 7;
    float g0 = 1.f/(1.f + expf(-(graw[(size_t)n*48 + hq*3 + 0] + bg[hq*3 + 0])));
    float g1 = 1.f/(1.f + expf(-(graw[(size_t)n*48 + hq*3 + 1] + bg[hq*3 + 1])));
    float g2 = 1.f/(1.f + expf(-(graw[(size_t)n*48 + hq*3 + 2] + bg[hq*3 + 2])));
    size_t idx = (size_t)n*DIM + c;
    ocomb[idx] = __float2bfloat16(b2f(cmp_o[idx])*g0 + b2f(fine_o[idx])*g1 + b2f(slide_o[idx])*g2);
  }
}

extern "C" void kernel_launch(void* const* d_in, const int* in_sizes, int n_in,
                              void* d_out, int out_size, void* d_ws, size_t ws_size,
                              hipStream_t stream)
{
  const float* x      = (const float*)d_in[0];
  const float* g_norm = (const float*)d_in[1];
  const float* W_qkv  = (const float*)d_in[2];
  const float* k_pos  = (const float*)d_in[3];
  const float* v_pos  = (const float*)d_in[4];
  const float* mem_kv = (const float*)d_in[5];
  const float* Wk1    = (const float*)d_in[6];
  const float* bk1    = (const float*)d_in[7];
  const float* Wk2    = (const float*)d_in[8];
  const float* bk2    = (const float*)d_in[9];
  const float* Wv1    = (const float*)d_in[10];
  const float* bv1    = (const float*)d_in[11];
  const float* Wv2    = (const float*)d_in[12];
  const float* bv2    = (const float*)d_in[13];
  const float* Wg     = (const float*)d_in[14];
  const float* bg     = (const float*)d_in[15];
  const float* W_out  = (const float*)d_in[16];
  float* out = (float*)d_out;
  (void)ws_size; (void)in_sizes; (void)n_in; (void)out_size;

  // ---- Workspace layout (bytes), total ~23.6 MB, aggressive region reuse ----
  char* base = (char*)d_ws;
  float* q     = (float*)(base + 0);                 // 8 MB [n][2048] fp32, live -> cmp_attn
  float* xn    = (float*)(base + 8388608);           // 8 MB fp32, live -> kv GEMM
  bf16*  qr    = (bf16*) (base + 8388608);           // 4 MB (over xn, after xn dead)
  bf16*  kr    = (bf16*) (base + 12582912);          // 0.5 MB
  bf16*  ocomb = (bf16*) (base + 8388608);           // 4 MB (over qr, after slide)
  float* kv    = (float*)(base + 16777216);          // 2 MB [n][512] fp32
  float* fbuf  = (float*)(base + 18874368);          // 2 MB fk / fv
  float* hbuf  = (float*)(base + 20971520);          // 2 MB hk / hv (raw, bias folded downstream)
  bf16*  cmp_o = (bf16*) (base + 18874368);          // 4 MB (over fbuf+hbuf, after MLPs)
  float* ckb   = (float*)(base + 23068672);          // 64 KB (raw)
  float* cvb   = (float*)(base + 23134208);          // 64 KB (raw)
  float* ck    = (float*)(base + 23199744);          // 65 KB
  float* cv    = (float*)(base + 23266304);          // 65 KB
  float* gates = (float*)(base + 23332864);          // 192 KB (raw, sigmoid folded in combine)
  int*   sel   = (int*)  (base + 23529472);          // 64 KB   (end: 23,595,008 B)
  bf16*  fine_o  = (bf16*)(base + 0);                // 4 MB (over q, after cmp_attn)
  bf16*  slide_o = (bf16*)(base + 4194304);          // 4 MB (over q upper half)

  // Zero split-K accumulation targets (stream-ordered; graph-capture legal)
  hipMemsetAsync(q,     0, (size_t)N_TOK*DIM*4,  stream);
  hipMemsetAsync(kv,    0, (size_t)N_TOK*512*4,  stream);
  hipMemsetAsync(gates, 0, (size_t)N_TOK*48*4,   stream);
  hipMemsetAsync(ckb,   0, (size_t)KVH*NWIN*DH*4, stream);
  hipMemsetAsync(cvb,   0, (size_t)KVH*NWIN*DH*4, stream);
  hipMemsetAsync(out,   0, (size_t)N_TOK*DIM*4,  stream);

  rmsnorm_kernel<<<N_TOK, 256, 0, stream>>>(x, g_norm, xn);
  // gates_raw = xn @ Wg            [1024 x 48],  S=8  -> 128 WGs
  gemm_splitk_kernel<<<dim3(1, 16, 8), 256, 0, stream>>>(xn, 0, nullptr, Wg, 48, gates, N_TOK, 48, DIM, 256);
  // q = xn @ W_qkv[:, 0:2048]      [1024 x 2048], S=4 -> 2048 WGs (selection-critical, fp32)
  gemm_splitk_kernel<<<dim3(32, 16, 4), 256, 0, stream>>>(xn, 0, nullptr, W_qkv, 2560, q, N_TOK, 2048, DIM, 512);
  // kv = xn @ W_qkv[:, 2048:2560]  [1024 x 512],  S=8 -> 1024 WGs
  gemm_splitk_kernel<<<dim3(8, 16, 8), 256, 0, stream>>>(xn, 0, nullptr, W_qkv + 2048, 2560, kv, N_TOK, 512, DIM, 256);
  // qr, kr (bf16) — xn now dead
  rope_kernel<<<N_TOK, 256, 0, stream>>>(q, kv, qr, kr);
  // compression MLPs (fp32, selection-critical via ck). relu(.+bk1) folded into MLP2 A-load; bk2 into assemble.
  build_f_kernel<<<KVH*NWIN, 256, 0, stream>>>(kv, 0, k_pos, fbuf);
  hipMemsetAsync(hbuf, 0, (size_t)KVH*NWIN*CDIM*4, stream);
  gemm_splitk_kernel<<<dim3(64, 2, 8),  256, 0, stream>>>(fbuf, 0, nullptr, Wk1, CDIM, hbuf, KVH*NWIN, CDIM, CDIM, 512);
  gemm_splitk_kernel<<<dim3(2, 2, 32),  256, 0, stream>>>(hbuf, 0, bk1,     Wk2, DH,   ckb,  KVH*NWIN, DH,   CDIM, 128);
  build_f_kernel<<<KVH*NWIN, 256, 0, stream>>>(kv, 256, v_pos, fbuf);
  hipMemsetAsync(hbuf, 0, (size_t)KVH*NWIN*CDIM*4, stream);
  gemm_splitk_kernel<<<dim3(64, 2, 8),  256, 0, stream>>>(fbuf, 0, nullptr, Wv1, CDIM, hbuf, KVH*NWIN, CDIM, CDIM, 512);
  gemm_splitk_kernel<<<dim3(2, 2, 32),  256, 0, stream>>>(hbuf, 0, bv1,     Wv2, DH,   cvb,  KVH*NWIN, DH,   CDIM, 128);
  assemble_kernel<<<NCMP, 256, 0, stream>>>(ckb, cvb, mem_kv, bk2, bv2, ck, cv);
  // compressed attention + selection (fbuf/hbuf dead -> cmp_o)
  cmp_attn_kernel<<<KVH*N_TOK, 256, 0, stream>>>(q, ck, cv, cmp_o, sel);
  // fine attention (q dead -> fine_o over q region)
  fine_attn_kernel<<<KVH*N_TOK, 256, 0, stream>>>(qr, kr, kv, sel, fine_o);
  // sliding attention (-> slide_o over q upper half)
  slide_attn_kernel<<<dim3(32, 16), 256, 0, stream>>>(qr, kr, kv, slide_o);
  // combine (qr dead -> ocomb over qr); sigmoid(graw+bg) folded here
  combine_kernel<<<N_TOK, 256, 0, stream>>>(cmp_o, fine_o, slide_o, gates, bg, ocomb);
  // out += ocomb @ W_out  (bf16 A, fp32 atomics), S=4 -> 2048 WGs
  gemm_splitk_kernel<<<dim3(32, 16, 4), 256, 0, stream>>>(ocomb, 1, nullptr, W_out, DIM, out, N_TOK, DIM, DIM, 512);
}